// Round 12
// baseline (620.834 us; speedup 1.0000x reference)
//
#include <hip/hip_runtime.h>
#include <stdint.h>

#define T_LEN 1460
#define NBT (256 * T_LEN)          // 373,760 (b,t) records
#define NREC (NBT * 16)            // 5,980,160 chain records
#define RSLOT 2304                 // ring slot: 1024 (A) + 1024 (B) + 256 (V)
#define NRING 8                    // slots per wave-private ring
#define WRING (NRING * RSLOT)      // 18432 B per wave
#define NWAVE 8                    // waves per block (2 per SIMD)

typedef __attribute__((address_space(3))) char lds_c;
typedef __attribute__((address_space(1))) const char g_c;

__device__ __forceinline__ float sigmf(float x) {
    float e = __builtin_amdgcn_exp2f(-1.44269504f * x);
    return __builtin_amdgcn_rcpf(1.0f + e);
}
__device__ __forceinline__ float rcpf(float x) { return __builtin_amdgcn_rcpf(x); }

// sum over each 16-lane row via full-rate DPP adds; result broadcast to all 16
__device__ __forceinline__ float row_sum16(float x) {
    x += __int_as_float(__builtin_amdgcn_update_dpp(0, __float_as_int(x), 0xB1, 0xF, 0xF, true));
    x += __int_as_float(__builtin_amdgcn_update_dpp(0, __float_as_int(x), 0x4E, 0xF, 0xF, true));
    x += __int_as_float(__builtin_amdgcn_update_dpp(0, __float_as_int(x), 0x141, 0xF, 0xF, true));
    x += __int_as_float(__builtin_amdgcn_update_dpp(0, __float_as_int(x), 0x140, 0xF, 0xF, true));
    return x;
}

// ---------------------------------------------------------------------------
// Kernel A (proven): pointwise parameter mapping.
// ---------------------------------------------------------------------------
__global__ __launch_bounds__(256) void shm_param_kernel(
    const float* __restrict__ xc, const float* __restrict__ lo,
    float* __restrict__ R, float* __restrict__ V)
{
    const int tid = blockIdx.x * 256 + threadIdx.x;
    const int m  = tid & 15;
    const int bt = tid >> 4;

    const float* lr = lo + (size_t)bt * 128 + m;
    const float r0 = lr[0],   r1 = lr[16],  r2 = lr[32],  r3 = lr[48];
    const float r4 = lr[64],  r5 = lr[80],  r6 = lr[96],  r7 = lr[112];

    const float* xp = xc + (size_t)bt * 3;
    const float prec = xp[0], pet = xp[1], temp = xp[2];
    const bool frozen = (temp < 0.f);
    const float tpos = frozen ? 0.f : temp;

    const float dd    = 10.f * sigmf(r0);
    const float sm    = tpos * dd;
    const float f_thr = fmaf(sigmf(r1), 50.f, 10.f);
    const float sumax = fmaf(sigmf(r2), 680.f, 20.f);
    const float beta  = fmaf(sigmf(r3), 5.f, 1.f);
    const float perc  = sigmf(r4);
    const float rkf   = rcpf(fmaf(sigmf(r5), 19.f, 1.f));
    const float rki   = rcpf(fmaf(sigmf(r6), 99.f, 1.f));
    const float rkb   = rcpf(fmaf(sigmf(r7), 990.f, 10.f));

    float4* Rp = (float4*)(R + (size_t)tid * 8);
    Rp[0] = make_float4(sm, f_thr, sumax, beta);
    Rp[1] = make_float4(perc, rkf, rki, rkb);
    if (m == 0)
        *(float4*)(V + (size_t)bt * 4) =
            make_float4(frozen ? prec : 0.f, frozen ? 0.f : prec, 0.9f * pet, 0.f);
}

// ---------------------------------------------------------------------------
// Kernel B: serial scan. 8 blocks x 8 waves (2 waves/SIMD -> TLP fills the
// ~45% stall cycles measured in round 11). Each wave is fully independent:
// private 8-slot LDS-DMA ring, per-wave counted vmcnt, no block sync.
// Region k (self-contained): vmcnt(9) -> ds_read t=4k..4k+3 -> lgkmcnt(0)
// -> DMA-issue t=4k+7..4k+10 -> 4x STEPC.
// Ledger: at region-k entry issued thru t=4k+6 (21 loads outstanding max),
// need t<=4k+3 -> vmcnt(9) for k<=363; region 364 -> vmcnt(0).
// WAR: overwrites (slots 4k+7..4k+10 mod 8) issue after lgkmcnt(0).
// ---------------------------------------------------------------------------
__global__ __launch_bounds__(512, 2) void shm_serial_kernel(
    const float* __restrict__ R,
    const float* __restrict__ V,
    float* __restrict__ out)
{
    __shared__ __align__(16) char ring[NWAVE * WRING];   // 147,456 B
    lds_c* ringc = (lds_c*)ring;

    const int lane = threadIdx.x & 63;
    const int wid  = threadIdx.x >> 6;
    const int m = lane & 15;
    const int chain = blockIdx.x * 512 + threadIdx.x;
    const int b = chain >> 4;

    lds_c* wring = ringc + wid * WRING;                  // wave-private ring
    const uint32_t ringB = (uint32_t)(uintptr_t)wring;

    const float* pRd = R + ((size_t)b * T_LEN * 16 + m) * 8;   // +128 fl/step
    const float* pVd = V + (size_t)b * T_LEN * 4 + (lane & 3); // +4 fl/step
    float* op = out + (size_t)b * T_LEN;

    const uint32_t vbp = ringB + lane * 16;                  // param read base
    const uint32_t vbv = ringB + 2048 + ((lane & ~3) << 2);  // V read base
    uint32_t roff = 0;   // read-slot base offset within wave ring (4-slot step)
    uint32_t woff = 0;   // next DMA slot offset within wave ring (1-slot step)

    float ss = 0.f, sf = 1.f, su = 5.f, si = 10.f, sb = 15.f;
    float qkeep = 0.f;

    float4 XA0,XB0,XV0, XA1,XB1,XV1, XA2,XB2,XV2, XA3,XB3,XV3;

#define DMA16(gp, loff) __builtin_amdgcn_global_load_lds((g_c*)(gp), wring + (loff), 16, 0, 0)
#define DMA4(gp, loff)  __builtin_amdgcn_global_load_lds((g_c*)(gp), wring + (loff), 4, 0, 0)

#define ISSUE1(tt) { if ((tt) < T_LEN) {                                     \
    DMA16(pRd,     woff);                                                    \
    DMA16(pRd + 4, woff + 1024);                                             \
    DMA4 (pVd,     woff + 2048);                                             \
    pRd += 128; pVd += 4;                                                    \
    woff += RSLOT; woff = (woff == WRING) ? 0u : woff; } }

#define RD3(DA, DB, DV, ap, av, OP1, OP2, OV)                                \
    asm volatile("ds_read_b128 %0, %3 offset:" OP1 "\n\t"                    \
                 "ds_read_b128 %1, %3 offset:" OP2 "\n\t"                    \
                 "ds_read_b128 %2, %4 offset:" OV                            \
                 : "=&v"(DA), "=&v"(DB), "=&v"(DV) : "v"(ap), "v"(av));

#define READ4() {                                                            \
    uint32_t ap = vbp + roff;                                                \
    uint32_t av = vbv + roff;                                                \
    RD3(XA0, XB0, XV0, ap, av, "0",    "1024", "0")                          \
    RD3(XA1, XB1, XV1, ap, av, "2304", "3328", "2304")                       \
    RD3(XA2, XB2, XV2, ap, av, "4608", "5632", "4608")                       \
    RD3(XA3, XB3, XV3, ap, av, "6912", "7936", "6912")                       \
    roff += 4 * RSLOT; roff = (roff == WRING) ? 0u : roff; }

#define STEPC(j, tt) {                                                       \
    const float smv = XA##j.x, f_thr = XA##j.y, sumax = XA##j.z,             \
                beta = XA##j.w;                                              \
    const float perc = XB##j.x, rkf = XB##j.y, rki = XB##j.z,                \
                rkb = XB##j.w;                                               \
    const float et09 = XV##j.z;                                              \
    const float inv = rcpf(sumax);                                           \
    const float pwp = 0.8f * sumax;                                          \
    const float e_i = et09 * inv;                                            \
    const float qs_out = fminf(ss, smv);                                     \
    ss = (ss - qs_out) + XV##j.x;                                            \
    const float qsp = qs_out + XV##j.y;                                      \
    const float qf_in = fmaxf(0.f, qsp - f_thr);                             \
    const float qu_in = fminf(qsp, f_thr);                                   \
    sf += qf_in; const float qf_out = sf * rkf; sf -= qf_out;                \
    const float u = su * inv;                                                \
    const float psi = __builtin_amdgcn_exp2f(beta * __builtin_amdgcn_logf(u)); \
    const float su_t = fmaf(qu_in, 1.f - psi, su);                           \
    const float su2 = fminf(su_t, sumax);                                    \
    const float ovf = fmaxf(0.f, su_t - sumax);                              \
    const float qu_out = fmaf(qu_in, psi, ovf);                              \
    const float ret = (su2 <= pwp) ? su2 * e_i : et09;                       \
    su = fmaxf(0.f, su2 - ret);                                              \
    const float qi_in = qu_out * perc;                                       \
    si += qi_in; const float qi_out = si * rki; si -= qi_out;                \
    const float qb_in = qu_out - qi_in;                                      \
    sb += qb_in; const float qb_out = sb * rkb; sb -= qb_out;                \
    const float q = row_sum16(qf_out + qi_out + qb_out) * 0.0625f;           \
    qkeep = (m == ((tt) & 15)) ? q : qkeep;                                  \
    if (((tt) & 15) == 15) op[((tt) & ~15) + m] = qkeep;                     \
}

#define REGION_W(k, WN) {                                                    \
    const int tbase = 4 * (k);                                               \
    asm volatile("s_waitcnt vmcnt(" WN ")" ::: "memory");                    \
    __builtin_amdgcn_sched_barrier(0);                                       \
    READ4()                                                                  \
    asm volatile("s_waitcnt lgkmcnt(0)" ::: "memory");                       \
    __builtin_amdgcn_sched_barrier(0);                                       \
    ISSUE1(tbase + 7) ISSUE1(tbase + 8)                                      \
    ISSUE1(tbase + 9) ISSUE1(tbase + 10)                                     \
    STEPC(0, tbase)     STEPC(1, tbase + 1)                                  \
    STEPC(2, tbase + 2) STEPC(3, tbase + 3)                                  \
}

    // prologue: issue slots t=0..6 (21 loads in flight)
    for (int j = 0; j < 7; ++j) { ISSUE1(j) }

    // regions 0..363: uniform vmcnt(9) ledger (issued thru 4k+6, need 4k+3)
    for (int k = 0; k < 364; ++k) {
        REGION_W(k, "9")
    }
    // region 364: reads t=1456..1459 (issuance ended at t=1459) -> drain
    REGION_W(364, "0")

    if (m < 4) op[1456 + m] = qkeep;   // t = 1456..1459 (held by m=0..3)

#undef DMA16
#undef DMA4
#undef ISSUE1
#undef RD3
#undef READ4
#undef STEPC
#undef REGION_W
}

// ---------------------------------------------------------------------------
// Fallback (proven round-2 kernel) if ws_size is too small.
// ---------------------------------------------------------------------------
#define CS 10
#define NCHUNK 146
#define IST 66

__device__ __forceinline__ float lane0f(float x) {
    return __int_as_float(__builtin_amdgcn_readlane(__float_as_int(x), 0));
}

__global__ __launch_bounds__(256, 1) void shm_pc_kernel(
    const float* __restrict__ xc, const float* __restrict__ lo,
    float* __restrict__ out)
{
    __shared__ float pbuf[2][CS][8][IST];
    __shared__ float bbuf[2][CS][4][4];

    const int lane  = threadIdx.x & 63;
    const int wid   = threadIdx.x >> 6;
    const int bbase = blockIdx.x * 4;

    const int ip = lane >> 3;
    const float A  = (ip==1)?10.f : (ip==2)?20.f : (ip==3)?1.f :
                     (ip==5)?1.f  : (ip==6)?1.f  : (ip==7)?10.f : 0.f;
    const float Bc = (ip==0)?10.f : (ip==1)?50.f : (ip==2)?680.f : (ip==3)?5.f :
                     (ip==4)?1.f  : (ip==5)?19.f : (ip==6)?99.f  : 990.f;
    const bool drcp = (ip >= 5);
    const bool dsm  = (ip == 0);
    const int  mm   = (2*lane) & 15;

    auto produce = [&](int cc, int buf) {
        const int t0 = cc * CS;
        float2 raw[14];
        float xr0[14], xr1[14], xr2[14];
#pragma unroll
        for (int r = 0; r < 14; ++r) {
            const int tau = (wid - 1) + 3 * r;
            if (tau < 40) {
                const int g  = tau / CS;
                const int tl = tau - g * CS;
                const size_t rowoff = (size_t)(bbase + g) * T_LEN + (t0 + tl);
                raw[r] = *(const float2*)(lo + rowoff * 128 + 2 * lane);
                if (lane == 0) {
                    const float* xp = xc + rowoff * 3;
                    xr0[r] = xp[0]; xr1[r] = xp[1]; xr2[r] = xp[2];
                }
            }
        }
#pragma unroll
        for (int r = 0; r < 14; ++r) {
            const int tau = (wid - 1) + 3 * r;
            if (tau < 40) {
                const int g  = tau / CS;
                const int tl = tau - g * CS;
                const float prec = lane0f(xr0[r]);
                const float pet  = lane0f(xr1[r]);
                const float temp = lane0f(xr2[r]);
                const bool frozen = (temp < 0.f);
                const float tpos = frozen ? 0.f : temp;
                const float sn   = frozen ? prec : 0.f;
                const float lpq  = frozen ? 0.f : prec;
                const float et09 = 0.9f * pet;

                float v0 = fmaf(sigmf(raw[r].x), Bc, A);
                float v1 = fmaf(sigmf(raw[r].y), Bc, A);
                v0 = drcp ? rcpf(v0) : v0;
                v1 = drcp ? rcpf(v1) : v1;
                v0 = dsm ? v0 * tpos : v0;
                v1 = dsm ? v1 * tpos : v1;

                float* dst = &pbuf[buf][tl][ip][g * 16 + mm];
                *(float2*)dst = make_float2(v0, v1);
                if (lane == 0)
                    *(float4*)&bbuf[buf][tl][g][0] = make_float4(sn, lpq, et09, 0.f);
            }
        }
    };

    const int g = lane >> 4, m = lane & 15;
    float ss = 0.f, sf = 1.f, su = 5.f, si = 10.f, sb = 15.f;
    float* op = out + (size_t)(bbase + g) * T_LEN;

    if (wid != 0) produce(0, 0);
    __syncthreads();

    for (int c = 0; c < NCHUNK; ++c) {
        if (wid == 0) {
            const int buf = c & 1;
#pragma unroll
            for (int tl = 0; tl < CS; ++tl) {
                const float* rec = &pbuf[buf][tl][0][lane];
                const float sm    = rec[0 * IST];
                const float f_thr = rec[1 * IST];
                const float sumax = rec[2 * IST];
                const float beta  = rec[3 * IST];
                const float perc  = rec[4 * IST];
                const float rkf   = rec[5 * IST];
                const float rki   = rec[6 * IST];
                const float rkb   = rec[7 * IST];
                const float4 bx = *(const float4*)&bbuf[buf][tl][g][0];

                float qs_out = fminf(ss, sm);
                ss = ss - qs_out + bx.x;
                float qsp = qs_out + bx.y;
                float qf_in = fmaxf(0.f, qsp - f_thr);
                float qu_in = fminf(qsp, f_thr);
                sf += qf_in;
                float qf_out = sf * rkf;
                sf -= qf_out;
                float inv_sumax = rcpf(sumax);
                float u = su * inv_sumax;
                float psi = __builtin_amdgcn_exp2f(beta * __builtin_amdgcn_logf(u));
                float su_temp = fmaf(qu_in, 1.f - psi, su);
                su = fminf(su_temp, sumax);
                float ovf = fmaxf(0.f, su_temp - sumax);
                float qu_out = fmaf(qu_in, psi, ovf);
                float pwp = 0.8f * sumax;
                float ktheta = (su <= pwp) ? su * inv_sumax : 1.f;
                float ret = bx.z * ktheta;
                su = fmaxf(0.f, su - ret);
                float qi_in = qu_out * perc;
                si += qi_in;
                float qi_out = si * rki;
                si -= qi_out;
                float qb_in = qu_out - qi_in;
                sb += qb_in;
                float qb_out = sb * rkb;
                sb -= qb_out;

                float q = row_sum16(qf_out + qi_out + qb_out) * 0.0625f;
                if (m == 0) op[c * CS + tl] = q;
            }
        } else if (c + 1 < NCHUNK) {
            produce(c + 1, (c + 1) & 1);
        }
        __syncthreads();
    }
}

extern "C" void kernel_launch(void* const* d_in, const int* in_sizes, int n_in,
                              void* d_out, int out_size, void* d_ws, size_t ws_size,
                              hipStream_t stream) {
    const float* xc = (const float*)d_in[0];   // [256,1460,3]
    const float* lo = (const float*)d_in[1];   // [256,1460,128]
    float* out = (float*)d_out;                // [256,1460,1]

    const size_t R_BYTES = (size_t)NREC * 32;  // 191,365,120
    const size_t V_BYTES = (size_t)NBT * 16;   //   5,980,160

    if (ws_size >= R_BYTES + V_BYTES) {
        float* R = (float*)d_ws;
        float* V = (float*)((char*)d_ws + R_BYTES);
        shm_param_kernel<<<dim3(NREC / 256), dim3(256), 0, stream>>>(xc, lo, R, V);
        shm_serial_kernel<<<dim3(8), dim3(512), 0, stream>>>(R, V, out);
    } else {
        shm_pc_kernel<<<dim3(64), dim3(256), 0, stream>>>(xc, lo, out);
    }
}

// Round 13
// 469.776 us; speedup vs baseline: 1.3216x; 1.3216x over previous
//
#include <hip/hip_runtime.h>
#include <stdint.h>

#define T_LEN 1460
#define NBT (256 * T_LEN)          // 373,760 (b,t) records
#define NREC (NBT * 16)            // 5,980,160 chain records
#define SSLOT 2304                 // per-chain-set sub-slot: 1024(A)+1024(B)+256(V)
#define RSLOT (2 * SSLOT)          // ring slot holds BOTH chain sets: 4608 B
#define NRING 8
#define WRING (NRING * RSLOT)      // 36864 B

typedef __attribute__((address_space(3))) char lds_c;
typedef __attribute__((address_space(1))) const char g_c;

__device__ __forceinline__ float sigmf(float x) {
    float e = __builtin_amdgcn_exp2f(-1.44269504f * x);
    return __builtin_amdgcn_rcpf(1.0f + e);
}
__device__ __forceinline__ float rcpf(float x) { return __builtin_amdgcn_rcpf(x); }

// sum over each 16-lane row via full-rate DPP adds; result broadcast to all 16
__device__ __forceinline__ float row_sum16(float x) {
    x += __int_as_float(__builtin_amdgcn_update_dpp(0, __float_as_int(x), 0xB1, 0xF, 0xF, true));
    x += __int_as_float(__builtin_amdgcn_update_dpp(0, __float_as_int(x), 0x4E, 0xF, 0xF, true));
    x += __int_as_float(__builtin_amdgcn_update_dpp(0, __float_as_int(x), 0x141, 0xF, 0xF, true));
    x += __int_as_float(__builtin_amdgcn_update_dpp(0, __float_as_int(x), 0x140, 0xF, 0xF, true));
    return x;
}

// ---------------------------------------------------------------------------
// Kernel A (proven): pointwise parameter mapping.
// ---------------------------------------------------------------------------
__global__ __launch_bounds__(256) void shm_param_kernel(
    const float* __restrict__ xc, const float* __restrict__ lo,
    float* __restrict__ R, float* __restrict__ V)
{
    const int tid = blockIdx.x * 256 + threadIdx.x;
    const int m  = tid & 15;
    const int bt = tid >> 4;

    const float* lr = lo + (size_t)bt * 128 + m;
    const float r0 = lr[0],   r1 = lr[16],  r2 = lr[32],  r3 = lr[48];
    const float r4 = lr[64],  r5 = lr[80],  r6 = lr[96],  r7 = lr[112];

    const float* xp = xc + (size_t)bt * 3;
    const float prec = xp[0], pet = xp[1], temp = xp[2];
    const bool frozen = (temp < 0.f);
    const float tpos = frozen ? 0.f : temp;

    const float dd    = 10.f * sigmf(r0);
    const float sm    = tpos * dd;
    const float f_thr = fmaf(sigmf(r1), 50.f, 10.f);
    const float sumax = fmaf(sigmf(r2), 680.f, 20.f);
    const float beta  = fmaf(sigmf(r3), 5.f, 1.f);
    const float perc  = sigmf(r4);
    const float rkf   = rcpf(fmaf(sigmf(r5), 19.f, 1.f));
    const float rki   = rcpf(fmaf(sigmf(r6), 99.f, 1.f));
    const float rkb   = rcpf(fmaf(sigmf(r7), 990.f, 10.f));

    float4* Rp = (float4*)(R + (size_t)tid * 8);
    Rp[0] = make_float4(sm, f_thr, sumax, beta);
    Rp[1] = make_float4(perc, rkf, rki, rkb);
    if (m == 0)
        *(float4*)(V + (size_t)bt * 4) =
            make_float4(frozen ? prec : 0.f, frozen ? 0.f : prec, 0.9f * pet, 0.f);
}

// ---------------------------------------------------------------------------
// Kernel B: serial scan, TWO independent chains per lane (in-stream ILP to
// fill the dep-stall bubbles measured in r11; avoids r12's per-CU contention).
// 32 blocks x 1 wave; each wave: basins 8*blk+g (set X) and 8*blk+4+g (set Z).
// Self-contained 4-step regions (proven r11 skeleton), ring slot = both sets.
// Ledger: 6 loads/step; prologue slots 0..6 (42 in flight); region k entry
// issued thru slot 4k+6, need <=4k+3 -> vmcnt(18) for k<=363; region 364 ->
// vmcnt(0). WAR: overwrites (slots 4k+7..4k+10 mod 8) issue after lgkmcnt(0).
// ---------------------------------------------------------------------------
__global__ __launch_bounds__(64, 1) void shm_serial_kernel(
    const float* __restrict__ R,
    const float* __restrict__ V,
    float* __restrict__ out)
{
    __shared__ __align__(16) char ring[WRING];
    lds_c* wring = (lds_c*)ring;
    const uint32_t ringB = (uint32_t)(uintptr_t)wring;

    const int lane = threadIdx.x;
    const int m = lane & 15;
    const int g = lane >> 4;
    const int b1 = blockIdx.x * 8 + g;
    const int b2 = b1 + 4;

    const float* pRd1 = R + ((size_t)b1 * T_LEN * 16 + m) * 8;
    const float* pVd1 = V + (size_t)b1 * T_LEN * 4 + (lane & 3);
    const float* pRd2 = R + ((size_t)b2 * T_LEN * 16 + m) * 8;
    const float* pVd2 = V + (size_t)b2 * T_LEN * 4 + (lane & 3);
    float* op1 = out + (size_t)b1 * T_LEN;
    float* op2 = out + (size_t)b2 * T_LEN;

    const uint32_t vbp = ringB + lane * 16;                  // param read base
    const uint32_t vbv = ringB + 2048 + ((lane & ~3) << 2);  // V read base
    uint32_t roff = 0;   // read-slot base (advances 4 slots)
    uint32_t woff = 0;   // next DMA slot (advances 1 slot)

    float ss1 = 0.f, sf1 = 1.f, su1 = 5.f, si1 = 10.f, sb1 = 15.f, qk1 = 0.f;
    float ss2 = 0.f, sf2 = 1.f, su2_ = 5.f, si2 = 10.f, sb2 = 15.f, qk2 = 0.f;

    float4 XA0,XB0,XV0, XA1,XB1,XV1, XA2,XB2,XV2, XA3,XB3,XV3;
    float4 ZA0,ZB0,ZV0, ZA1,ZB1,ZV1, ZA2,ZB2,ZV2, ZA3,ZB3,ZV3;

#define DMA16(gp, loff) __builtin_amdgcn_global_load_lds((g_c*)(gp), wring + (loff), 16, 0, 0)
#define DMA4(gp, loff)  __builtin_amdgcn_global_load_lds((g_c*)(gp), wring + (loff), 4, 0, 0)

#define ISSUE1(tt) { if ((tt) < T_LEN) {                                     \
    DMA16(pRd1,     woff);                                                   \
    DMA16(pRd1 + 4, woff + 1024);                                            \
    DMA4 (pVd1,     woff + 2048);                                            \
    DMA16(pRd2,     woff + 2304);                                            \
    DMA16(pRd2 + 4, woff + 3328);                                            \
    DMA4 (pVd2,     woff + 4352);                                            \
    pRd1 += 128; pVd1 += 4; pRd2 += 128; pVd2 += 4;                          \
    woff += RSLOT; woff = (woff == WRING) ? 0u : woff; } }

#define RD3(DA, DB, DV, ap, av, OP1, OP2, OV)                                \
    asm volatile("ds_read_b128 %0, %3 offset:" OP1 "\n\t"                    \
                 "ds_read_b128 %1, %3 offset:" OP2 "\n\t"                    \
                 "ds_read_b128 %2, %4 offset:" OV                            \
                 : "=&v"(DA), "=&v"(DB), "=&v"(DV) : "v"(ap), "v"(av));

#define READ4() {                                                            \
    uint32_t ap = vbp + roff;                                                \
    uint32_t av = vbv + roff;                                                \
    RD3(XA0, XB0, XV0, ap, av, "0",     "1024",  "0")                        \
    RD3(ZA0, ZB0, ZV0, ap, av, "2304",  "3328",  "2304")                     \
    RD3(XA1, XB1, XV1, ap, av, "4608",  "5632",  "4608")                     \
    RD3(ZA1, ZB1, ZV1, ap, av, "6912",  "7936",  "6912")                     \
    RD3(XA2, XB2, XV2, ap, av, "9216",  "10240", "9216")                     \
    RD3(ZA2, ZB2, ZV2, ap, av, "11520", "12544", "11520")                    \
    RD3(XA3, XB3, XV3, ap, av, "13824", "14848", "13824")                    \
    RD3(ZA3, ZB3, ZV3, ap, av, "16128", "17152", "16128")                    \
    roff += 4 * RSLOT; roff = (roff == WRING) ? 0u : roff; }

#define STEPB(PA, PB, PV, ss, sf, su, si, sb, qk, opx, tt) {                 \
    const float smv = PA.x, f_thr = PA.y, sumax = PA.z, beta = PA.w;         \
    const float perc = PB.x, rkf = PB.y, rki = PB.z, rkb = PB.w;             \
    const float et09 = PV.z;                                                 \
    const float inv = rcpf(sumax);                                           \
    const float e_i = et09 * inv;                                            \
    const float qs_out = fminf(ss, smv);                                     \
    ss = (ss - qs_out) + PV.x;                                               \
    const float qsp = qs_out + PV.y;                                         \
    const float qf_in = fmaxf(0.f, qsp - f_thr);                             \
    const float qu_in = fminf(qsp, f_thr);                                   \
    sf += qf_in; const float qf_out = sf * rkf; sf -= qf_out;                \
    const float u = su * inv;                                                \
    const float psi = __builtin_amdgcn_exp2f(beta * __builtin_amdgcn_logf(u)); \
    const float su_t = fmaf(qu_in, 1.f - psi, su);                           \
    const float suc = fminf(su_t, sumax);                                    \
    const float ovf = fmaxf(0.f, su_t - sumax);                              \
    const float qu_out = fmaf(qu_in, psi, ovf);                              \
    const float u2 = suc * inv;                                              \
    const float ret = (u2 <= 0.8f) ? suc * e_i : et09;                       \
    su = fmaxf(0.f, suc - ret);                                              \
    const float qi_in = qu_out * perc;                                       \
    si += qi_in; const float qi_out = si * rki; si -= qi_out;                \
    const float qb_in = qu_out - qi_in;                                      \
    sb += qb_in; const float qb_out = sb * rkb; sb -= qb_out;                \
    const float q = row_sum16(qf_out + qi_out + qb_out) * 0.0625f;           \
    qk = (m == ((tt) & 15)) ? q : qk;                                        \
    if (((tt) & 15) == 15) opx[((tt) & ~15) + m] = qk;                       \
}

#define STEP2(j, tt)                                                         \
    STEPB(XA##j, XB##j, XV##j, ss1, sf1, su1,  si1, sb1, qk1, op1, (tt))     \
    STEPB(ZA##j, ZB##j, ZV##j, ss2, sf2, su2_, si2, sb2, qk2, op2, (tt))

#define REGION_W(k, WN) {                                                    \
    const int tbase = 4 * (k);                                               \
    asm volatile("s_waitcnt vmcnt(" WN ")" ::: "memory");                    \
    __builtin_amdgcn_sched_barrier(0);                                       \
    READ4()                                                                  \
    asm volatile("s_waitcnt lgkmcnt(0)" ::: "memory");                       \
    __builtin_amdgcn_sched_barrier(0);                                       \
    ISSUE1(tbase + 7) ISSUE1(tbase + 8)                                      \
    ISSUE1(tbase + 9) ISSUE1(tbase + 10)                                     \
    STEP2(0, tbase)     STEP2(1, tbase + 1)                                  \
    STEP2(2, tbase + 2) STEP2(3, tbase + 3)                                  \
}

    // prologue: issue slots t=0..6 (42 loads in flight)
    for (int j = 0; j < 7; ++j) { ISSUE1(j) }

    // regions 0..363: uniform vmcnt(18) (issued thru 4k+6, need 4k+3)
    for (int k = 0; k < 364; ++k) {
        REGION_W(k, "18")
    }
    // region 364: reads t=1456..1459 (issuance ended at t=1459) -> drain
    REGION_W(364, "0")

    if (m < 4) { op1[1456 + m] = qk1; op2[1456 + m] = qk2; }

#undef DMA16
#undef DMA4
#undef ISSUE1
#undef RD3
#undef READ4
#undef STEPB
#undef STEP2
#undef REGION_W
}

// ---------------------------------------------------------------------------
// Fallback (proven round-2 kernel) if ws_size is too small.
// ---------------------------------------------------------------------------
#define CS 10
#define NCHUNK 146
#define IST 66

__device__ __forceinline__ float lane0f(float x) {
    return __int_as_float(__builtin_amdgcn_readlane(__float_as_int(x), 0));
}

__global__ __launch_bounds__(256, 1) void shm_pc_kernel(
    const float* __restrict__ xc, const float* __restrict__ lo,
    float* __restrict__ out)
{
    __shared__ float pbuf[2][CS][8][IST];
    __shared__ float bbuf[2][CS][4][4];

    const int lane  = threadIdx.x & 63;
    const int wid   = threadIdx.x >> 6;
    const int bbase = blockIdx.x * 4;

    const int ip = lane >> 3;
    const float A  = (ip==1)?10.f : (ip==2)?20.f : (ip==3)?1.f :
                     (ip==5)?1.f  : (ip==6)?1.f  : (ip==7)?10.f : 0.f;
    const float Bc = (ip==0)?10.f : (ip==1)?50.f : (ip==2)?680.f : (ip==3)?5.f :
                     (ip==4)?1.f  : (ip==5)?19.f : (ip==6)?99.f  : 990.f;
    const bool drcp = (ip >= 5);
    const bool dsm  = (ip == 0);
    const int  mm   = (2*lane) & 15;

    auto produce = [&](int cc, int buf) {
        const int t0 = cc * CS;
        float2 raw[14];
        float xr0[14], xr1[14], xr2[14];
#pragma unroll
        for (int r = 0; r < 14; ++r) {
            const int tau = (wid - 1) + 3 * r;
            if (tau < 40) {
                const int g  = tau / CS;
                const int tl = tau - g * CS;
                const size_t rowoff = (size_t)(bbase + g) * T_LEN + (t0 + tl);
                raw[r] = *(const float2*)(lo + rowoff * 128 + 2 * lane);
                if (lane == 0) {
                    const float* xp = xc + rowoff * 3;
                    xr0[r] = xp[0]; xr1[r] = xp[1]; xr2[r] = xp[2];
                }
            }
        }
#pragma unroll
        for (int r = 0; r < 14; ++r) {
            const int tau = (wid - 1) + 3 * r;
            if (tau < 40) {
                const int g  = tau / CS;
                const int tl = tau - g * CS;
                const float prec = lane0f(xr0[r]);
                const float pet  = lane0f(xr1[r]);
                const float temp = lane0f(xr2[r]);
                const bool frozen = (temp < 0.f);
                const float tpos = frozen ? 0.f : temp;
                const float sn   = frozen ? prec : 0.f;
                const float lpq  = frozen ? 0.f : prec;
                const float et09 = 0.9f * pet;

                float v0 = fmaf(sigmf(raw[r].x), Bc, A);
                float v1 = fmaf(sigmf(raw[r].y), Bc, A);
                v0 = drcp ? rcpf(v0) : v0;
                v1 = drcp ? rcpf(v1) : v1;
                v0 = dsm ? v0 * tpos : v0;
                v1 = dsm ? v1 * tpos : v1;

                float* dst = &pbuf[buf][tl][ip][g * 16 + mm];
                *(float2*)dst = make_float2(v0, v1);
                if (lane == 0)
                    *(float4*)&bbuf[buf][tl][g][0] = make_float4(sn, lpq, et09, 0.f);
            }
        }
    };

    const int g = lane >> 4, m = lane & 15;
    float ss = 0.f, sf = 1.f, su = 5.f, si = 10.f, sb = 15.f;
    float* op = out + (size_t)(bbase + g) * T_LEN;

    if (wid != 0) produce(0, 0);
    __syncthreads();

    for (int c = 0; c < NCHUNK; ++c) {
        if (wid == 0) {
            const int buf = c & 1;
#pragma unroll
            for (int tl = 0; tl < CS; ++tl) {
                const float* rec = &pbuf[buf][tl][0][lane];
                const float sm    = rec[0 * IST];
                const float f_thr = rec[1 * IST];
                const float sumax = rec[2 * IST];
                const float beta  = rec[3 * IST];
                const float perc  = rec[4 * IST];
                const float rkf   = rec[5 * IST];
                const float rki   = rec[6 * IST];
                const float rkb   = rec[7 * IST];
                const float4 bx = *(const float4*)&bbuf[buf][tl][g][0];

                float qs_out = fminf(ss, sm);
                ss = ss - qs_out + bx.x;
                float qsp = qs_out + bx.y;
                float qf_in = fmaxf(0.f, qsp - f_thr);
                float qu_in = fminf(qsp, f_thr);
                sf += qf_in;
                float qf_out = sf * rkf;
                sf -= qf_out;
                float inv_sumax = rcpf(sumax);
                float u = su * inv_sumax;
                float psi = __builtin_amdgcn_exp2f(beta * __builtin_amdgcn_logf(u));
                float su_temp = fmaf(qu_in, 1.f - psi, su);
                su = fminf(su_temp, sumax);
                float ovf = fmaxf(0.f, su_temp - sumax);
                float qu_out = fmaf(qu_in, psi, ovf);
                float pwp = 0.8f * sumax;
                float ktheta = (su <= pwp) ? su * inv_sumax : 1.f;
                float ret = bx.z * ktheta;
                su = fmaxf(0.f, su - ret);
                float qi_in = qu_out * perc;
                si += qi_in;
                float qi_out = si * rki;
                si -= qi_out;
                float qb_in = qu_out - qi_in;
                sb += qb_in;
                float qb_out = sb * rkb;
                sb -= qb_out;

                float q = row_sum16(qf_out + qi_out + qb_out) * 0.0625f;
                if (m == 0) op[c * CS + tl] = q;
            }
        } else if (c + 1 < NCHUNK) {
            produce(c + 1, (c + 1) & 1);
        }
        __syncthreads();
    }
}

extern "C" void kernel_launch(void* const* d_in, const int* in_sizes, int n_in,
                              void* d_out, int out_size, void* d_ws, size_t ws_size,
                              hipStream_t stream) {
    const float* xc = (const float*)d_in[0];   // [256,1460,3]
    const float* lo = (const float*)d_in[1];   // [256,1460,128]
    float* out = (float*)d_out;                // [256,1460,1]

    const size_t R_BYTES = (size_t)NREC * 32;  // 191,365,120
    const size_t V_BYTES = (size_t)NBT * 16;   //   5,980,160

    if (ws_size >= R_BYTES + V_BYTES) {
        float* R = (float*)d_ws;
        float* V = (float*)((char*)d_ws + R_BYTES);
        shm_param_kernel<<<dim3(NREC / 256), dim3(256), 0, stream>>>(xc, lo, R, V);
        shm_serial_kernel<<<dim3(32), dim3(64), 0, stream>>>(R, V, out);
    } else {
        shm_pc_kernel<<<dim3(64), dim3(256), 0, stream>>>(xc, lo, out);
    }
}

// Round 14
// 272.973 us; speedup vs baseline: 2.2743x; 1.7210x over previous
//
#include <hip/hip_runtime.h>
#include <stdint.h>

#define T_LEN 1460
#define NBT (256 * T_LEN)          // 373,760 (b,t) records
#define NREC (NBT * 16)            // 5,980,160 chain records
#define RSLOT 2304                 // slot: 1024 (A) + 1024 (B) + 256 (V)
#define HSLOTS 10                  // slots per half (10-step region)
#define HBYTES (HSLOTS * RSLOT)    // 23040
#define RINGSZ (2 * HBYTES)        // 46080

typedef __attribute__((address_space(3))) char lds_c;
typedef __attribute__((address_space(1))) const char g_c;

__device__ __forceinline__ float sigmf(float x) {
    float e = __builtin_amdgcn_exp2f(-1.44269504f * x);
    return __builtin_amdgcn_rcpf(1.0f + e);
}
__device__ __forceinline__ float rcpf(float x) { return __builtin_amdgcn_rcpf(x); }

// sum over each 16-lane row via full-rate DPP adds; result broadcast to all 16
__device__ __forceinline__ float row_sum16(float x) {
    x += __int_as_float(__builtin_amdgcn_update_dpp(0, __float_as_int(x), 0xB1, 0xF, 0xF, true));
    x += __int_as_float(__builtin_amdgcn_update_dpp(0, __float_as_int(x), 0x4E, 0xF, 0xF, true));
    x += __int_as_float(__builtin_amdgcn_update_dpp(0, __float_as_int(x), 0x141, 0xF, 0xF, true));
    x += __int_as_float(__builtin_amdgcn_update_dpp(0, __float_as_int(x), 0x140, 0xF, 0xF, true));
    return x;
}

// ---------------------------------------------------------------------------
// Kernel A (proven): pointwise parameter mapping.
// ---------------------------------------------------------------------------
__global__ __launch_bounds__(256) void shm_param_kernel(
    const float* __restrict__ xc, const float* __restrict__ lo,
    float* __restrict__ R, float* __restrict__ V)
{
    const int tid = blockIdx.x * 256 + threadIdx.x;
    const int m  = tid & 15;
    const int bt = tid >> 4;

    const float* lr = lo + (size_t)bt * 128 + m;
    const float r0 = lr[0],   r1 = lr[16],  r2 = lr[32],  r3 = lr[48];
    const float r4 = lr[64],  r5 = lr[80],  r6 = lr[96],  r7 = lr[112];

    const float* xp = xc + (size_t)bt * 3;
    const float prec = xp[0], pet = xp[1], temp = xp[2];
    const bool frozen = (temp < 0.f);
    const float tpos = frozen ? 0.f : temp;

    const float dd    = 10.f * sigmf(r0);
    const float sm    = tpos * dd;
    const float f_thr = fmaf(sigmf(r1), 50.f, 10.f);
    const float sumax = fmaf(sigmf(r2), 680.f, 20.f);
    const float beta  = fmaf(sigmf(r3), 5.f, 1.f);
    const float perc  = sigmf(r4);
    const float rkf   = rcpf(fmaf(sigmf(r5), 19.f, 1.f));
    const float rki   = rcpf(fmaf(sigmf(r6), 99.f, 1.f));
    const float rkb   = rcpf(fmaf(sigmf(r7), 990.f, 10.f));

    float4* Rp = (float4*)(R + (size_t)tid * 8);
    Rp[0] = make_float4(sm, f_thr, sumax, beta);
    Rp[1] = make_float4(perc, rkf, rki, rkb);
    if (m == 0)
        *(float4*)(V + (size_t)bt * 4) =
            make_float4(frozen ? prec : 0.f, frozen ? 0.f : prec, 0.9f * pet, 0.f);
}

// ---------------------------------------------------------------------------
// Kernel B: serial scan, 10-step double-buffered regions (fence amortization).
// Region r: vmcnt(0) [prev region's DMAs landed; free in steady state since
// they were issued ~2500 cy earlier] -> 30 ds_read from half[r&1] ->
// lgkmcnt(0) -> issue 30 DMAs into half[(r+1)&1] -> 10 STEPCs.
// WAR: issues into half[c^1] follow this region's lgkm(0); that half's reads
// finished in region r-1. RAW: reads of half[c] covered by vmcnt(0).
// 1460 = 146 * 10 exactly -> no ragged tail.
// ---------------------------------------------------------------------------
__global__ __launch_bounds__(64, 1) void shm_serial_kernel(
    const float* __restrict__ R,
    const float* __restrict__ V,
    float* __restrict__ out)
{
    __shared__ __align__(16) char ring[RINGSZ];
    lds_c* wring = (lds_c*)ring;
    const uint32_t ringB = (uint32_t)(uintptr_t)wring;

    const int lane = threadIdx.x;
    const int m = lane & 15;
    const int b = (blockIdx.x * 64 + lane) >> 4;

    const float* pRd = R + ((size_t)b * T_LEN * 16 + m) * 8;   // +128 fl/step
    const float* pVd = V + (size_t)b * T_LEN * 4 + (lane & 3); // +4 fl/step
    float* op = out + (size_t)b * T_LEN;

    const uint32_t vbp = ringB + lane * 16;                  // param read base
    const uint32_t vbv = ringB + 2048 + ((lane & ~3) << 2);  // V read base

    float ss = 0.f, sf = 1.f, su = 5.f, si = 10.f, sb = 15.f;
    float qkeep = 0.f;

    float4 A0,B0,W0, A1,B1,W1, A2,B2,W2, A3,B3,W3, A4,B4,W4;
    float4 A5,B5,W5, A6,B6,W6, A7,B7,W7, A8,B8,W8, A9,B9,W9;

#define DMA16(gp, loff) __builtin_amdgcn_global_load_lds((g_c*)(gp), wring + (loff), 16, 0, 0)
#define DMA4(gp, loff)  __builtin_amdgcn_global_load_lds((g_c*)(gp), wring + (loff), 4, 0, 0)

#define ISSUE1(wb, J) {                                                      \
    DMA16(pRd,     (wb) + (J) * RSLOT);                                      \
    DMA16(pRd + 4, (wb) + (J) * RSLOT + 1024);                               \
    DMA4 (pVd,     (wb) + (J) * RSLOT + 2048);                               \
    pRd += 128; pVd += 4; }

#define RD3(DA, DB, DV, ap, av, OP1, OP2, OV)                                \
    asm volatile("ds_read_b128 %0, %3 offset:" OP1 "\n\t"                    \
                 "ds_read_b128 %1, %3 offset:" OP2 "\n\t"                    \
                 "ds_read_b128 %2, %4 offset:" OV                            \
                 : "=&v"(DA), "=&v"(DB), "=&v"(DV) : "v"(ap), "v"(av));

#define READ10(roff) {                                                       \
    uint32_t ap = vbp + (roff);                                              \
    uint32_t av = vbv + (roff);                                              \
    RD3(A0,B0,W0, ap,av, "0",     "1024",  "0")                              \
    RD3(A1,B1,W1, ap,av, "2304",  "3328",  "2304")                           \
    RD3(A2,B2,W2, ap,av, "4608",  "5632",  "4608")                           \
    RD3(A3,B3,W3, ap,av, "6912",  "7936",  "6912")                           \
    RD3(A4,B4,W4, ap,av, "9216",  "10240", "9216")                           \
    RD3(A5,B5,W5, ap,av, "11520", "12544", "11520")                          \
    RD3(A6,B6,W6, ap,av, "13824", "14848", "13824")                          \
    RD3(A7,B7,W7, ap,av, "16128", "17152", "16128")                          \
    RD3(A8,B8,W8, ap,av, "18432", "19456", "18432")                          \
    RD3(A9,B9,W9, ap,av, "20736", "21760", "20736")                          \
}

#define STEPC(J, tt) {                                                       \
    const float smv = A##J.x, f_thr = A##J.y, sumax = A##J.z, beta = A##J.w; \
    const float perc = B##J.x, rkf = B##J.y, rki = B##J.z, rkb = B##J.w;     \
    const float et09 = W##J.z;                                               \
    const float inv = rcpf(sumax);                                           \
    const float pwp = 0.8f * sumax;                                          \
    const float e_i = et09 * inv;                                            \
    const float qs_out = fminf(ss, smv);                                     \
    ss = (ss - qs_out) + W##J.x;                                             \
    const float qsp = qs_out + W##J.y;                                       \
    const float qf_in = fmaxf(0.f, qsp - f_thr);                             \
    const float qu_in = fminf(qsp, f_thr);                                   \
    sf += qf_in; const float qf_out = sf * rkf; sf -= qf_out;                \
    const float u = su * inv;                                                \
    const float psi = __builtin_amdgcn_exp2f(beta * __builtin_amdgcn_logf(u)); \
    const float su_t = fmaf(qu_in, 1.f - psi, su);                           \
    const float su2 = fminf(su_t, sumax);                                    \
    const float ovf = fmaxf(0.f, su_t - sumax);                              \
    const float qu_out = fmaf(qu_in, psi, ovf);                              \
    const float ret = (su2 <= pwp) ? su2 * e_i : et09;                       \
    su = fmaxf(0.f, su2 - ret);                                              \
    const float qi_in = qu_out * perc;                                       \
    si += qi_in; const float qi_out = si * rki; si -= qi_out;                \
    const float qb_in = qu_out - qi_in;                                      \
    sb += qb_in; const float qb_out = sb * rkb; sb -= qb_out;                \
    const float q = row_sum16(qf_out + qi_out + qb_out) * 0.0625f;           \
    qkeep = (m == ((tt) & 15)) ? q : qkeep;                                  \
    if (((tt) & 15) == 15) op[((tt) & ~15) + m] = qkeep;                     \
}

    // prologue: fill half 0 with t = 0..9
    {
        ISSUE1(0u, 0) ISSUE1(0u, 1) ISSUE1(0u, 2) ISSUE1(0u, 3) ISSUE1(0u, 4)
        ISSUE1(0u, 5) ISSUE1(0u, 6) ISSUE1(0u, 7) ISSUE1(0u, 8) ISSUE1(0u, 9)
    }

    for (int r = 0; r < 146; ++r) {
        const int tbase = 10 * r;
        asm volatile("s_waitcnt vmcnt(0)" ::: "memory");
        __builtin_amdgcn_sched_barrier(0);
        READ10((uint32_t)(r & 1) * HBYTES)
        asm volatile("s_waitcnt lgkmcnt(0)" ::: "memory");
        __builtin_amdgcn_sched_barrier(0);
        if (r < 145) {
            const uint32_t wb = (uint32_t)((r + 1) & 1) * HBYTES;
            ISSUE1(wb, 0) ISSUE1(wb, 1) ISSUE1(wb, 2) ISSUE1(wb, 3)
            ISSUE1(wb, 4) ISSUE1(wb, 5) ISSUE1(wb, 6) ISSUE1(wb, 7)
            ISSUE1(wb, 8) ISSUE1(wb, 9)
        }
        STEPC(0, tbase)     STEPC(1, tbase + 1) STEPC(2, tbase + 2)
        STEPC(3, tbase + 3) STEPC(4, tbase + 4) STEPC(5, tbase + 5)
        STEPC(6, tbase + 6) STEPC(7, tbase + 7) STEPC(8, tbase + 8)
        STEPC(9, tbase + 9)
    }

    if (m < 4) op[1456 + m] = qkeep;   // t = 1456..1459 (held by m=0..3)

#undef DMA16
#undef DMA4
#undef ISSUE1
#undef RD3
#undef READ10
#undef STEPC
}

// ---------------------------------------------------------------------------
// Fallback (proven round-2 kernel) if ws_size is too small.
// ---------------------------------------------------------------------------
#define CS 10
#define NCHUNK 146
#define IST 66

__device__ __forceinline__ float lane0f(float x) {
    return __int_as_float(__builtin_amdgcn_readlane(__float_as_int(x), 0));
}

__global__ __launch_bounds__(256, 1) void shm_pc_kernel(
    const float* __restrict__ xc, const float* __restrict__ lo,
    float* __restrict__ out)
{
    __shared__ float pbuf[2][CS][8][IST];
    __shared__ float bbuf[2][CS][4][4];

    const int lane  = threadIdx.x & 63;
    const int wid   = threadIdx.x >> 6;
    const int bbase = blockIdx.x * 4;

    const int ip = lane >> 3;
    const float A  = (ip==1)?10.f : (ip==2)?20.f : (ip==3)?1.f :
                     (ip==5)?1.f  : (ip==6)?1.f  : (ip==7)?10.f : 0.f;
    const float Bc = (ip==0)?10.f : (ip==1)?50.f : (ip==2)?680.f : (ip==3)?5.f :
                     (ip==4)?1.f  : (ip==5)?19.f : (ip==6)?99.f  : 990.f;
    const bool drcp = (ip >= 5);
    const bool dsm  = (ip == 0);
    const int  mm   = (2*lane) & 15;

    auto produce = [&](int cc, int buf) {
        const int t0 = cc * CS;
        float2 raw[14];
        float xr0[14], xr1[14], xr2[14];
#pragma unroll
        for (int r = 0; r < 14; ++r) {
            const int tau = (wid - 1) + 3 * r;
            if (tau < 40) {
                const int g  = tau / CS;
                const int tl = tau - g * CS;
                const size_t rowoff = (size_t)(bbase + g) * T_LEN + (t0 + tl);
                raw[r] = *(const float2*)(lo + rowoff * 128 + 2 * lane);
                if (lane == 0) {
                    const float* xp = xc + rowoff * 3;
                    xr0[r] = xp[0]; xr1[r] = xp[1]; xr2[r] = xp[2];
                }
            }
        }
#pragma unroll
        for (int r = 0; r < 14; ++r) {
            const int tau = (wid - 1) + 3 * r;
            if (tau < 40) {
                const int g  = tau / CS;
                const int tl = tau - g * CS;
                const float prec = lane0f(xr0[r]);
                const float pet  = lane0f(xr1[r]);
                const float temp = lane0f(xr2[r]);
                const bool frozen = (temp < 0.f);
                const float tpos = frozen ? 0.f : temp;
                const float sn   = frozen ? prec : 0.f;
                const float lpq  = frozen ? 0.f : prec;
                const float et09 = 0.9f * pet;

                float v0 = fmaf(sigmf(raw[r].x), Bc, A);
                float v1 = fmaf(sigmf(raw[r].y), Bc, A);
                v0 = drcp ? rcpf(v0) : v0;
                v1 = drcp ? rcpf(v1) : v1;
                v0 = dsm ? v0 * tpos : v0;
                v1 = dsm ? v1 * tpos : v1;

                float* dst = &pbuf[buf][tl][ip][g * 16 + mm];
                *(float2*)dst = make_float2(v0, v1);
                if (lane == 0)
                    *(float4*)&bbuf[buf][tl][g][0] = make_float4(sn, lpq, et09, 0.f);
            }
        }
    };

    const int g = lane >> 4, m = lane & 15;
    float ss = 0.f, sf = 1.f, su = 5.f, si = 10.f, sb = 15.f;
    float* op = out + (size_t)(bbase + g) * T_LEN;

    if (wid != 0) produce(0, 0);
    __syncthreads();

    for (int c = 0; c < NCHUNK; ++c) {
        if (wid == 0) {
            const int buf = c & 1;
#pragma unroll
            for (int tl = 0; tl < CS; ++tl) {
                const float* rec = &pbuf[buf][tl][0][lane];
                const float sm    = rec[0 * IST];
                const float f_thr = rec[1 * IST];
                const float sumax = rec[2 * IST];
                const float beta  = rec[3 * IST];
                const float perc  = rec[4 * IST];
                const float rkf   = rec[5 * IST];
                const float rki   = rec[6 * IST];
                const float rkb   = rec[7 * IST];
                const float4 bx = *(const float4*)&bbuf[buf][tl][g][0];

                float qs_out = fminf(ss, sm);
                ss = ss - qs_out + bx.x;
                float qsp = qs_out + bx.y;
                float qf_in = fmaxf(0.f, qsp - f_thr);
                float qu_in = fminf(qsp, f_thr);
                sf += qf_in;
                float qf_out = sf * rkf;
                sf -= qf_out;
                float inv_sumax = rcpf(sumax);
                float u = su * inv_sumax;
                float psi = __builtin_amdgcn_exp2f(beta * __builtin_amdgcn_logf(u));
                float su_temp = fmaf(qu_in, 1.f - psi, su);
                su = fminf(su_temp, sumax);
                float ovf = fmaxf(0.f, su_temp - sumax);
                float qu_out = fmaf(qu_in, psi, ovf);
                float pwp = 0.8f * sumax;
                float ktheta = (su <= pwp) ? su * inv_sumax : 1.f;
                float ret = bx.z * ktheta;
                su = fmaxf(0.f, su - ret);
                float qi_in = qu_out * perc;
                si += qi_in;
                float qi_out = si * rki;
                si -= qi_out;
                float qb_in = qu_out - qi_in;
                sb += qb_in;
                float qb_out = sb * rkb;
                sb -= qb_out;

                float q = row_sum16(qf_out + qi_out + qb_out) * 0.0625f;
                if (m == 0) op[c * CS + tl] = q;
            }
        } else if (c + 1 < NCHUNK) {
            produce(c + 1, (c + 1) & 1);
        }
        __syncthreads();
    }
}

extern "C" void kernel_launch(void* const* d_in, const int* in_sizes, int n_in,
                              void* d_out, int out_size, void* d_ws, size_t ws_size,
                              hipStream_t stream) {
    const float* xc = (const float*)d_in[0];   // [256,1460,3]
    const float* lo = (const float*)d_in[1];   // [256,1460,128]
    float* out = (float*)d_out;                // [256,1460,1]

    const size_t R_BYTES = (size_t)NREC * 32;  // 191,365,120
    const size_t V_BYTES = (size_t)NBT * 16;   //   5,980,160

    if (ws_size >= R_BYTES + V_BYTES) {
        float* R = (float*)d_ws;
        float* V = (float*)((char*)d_ws + R_BYTES);
        shm_param_kernel<<<dim3(NREC / 256), dim3(256), 0, stream>>>(xc, lo, R, V);
        shm_serial_kernel<<<dim3(64), dim3(64), 0, stream>>>(R, V, out);
    } else {
        shm_pc_kernel<<<dim3(64), dim3(256), 0, stream>>>(xc, lo, out);
    }
}

// Round 15
// 210.312 us; speedup vs baseline: 2.9520x; 1.2979x over previous
//
#include <hip/hip_runtime.h>
#include <stdint.h>

#define T_LEN 1460
#define NBT (256 * T_LEN)          // 373,760 (b,t) records
#define NREC (NBT * 16)            // 5,980,160 chain records
#define RSLOT 2304                 // slot: 1024 (A) + 1024 (B) + 256 (V)
#define HSLOTS 10                  // slots per half (10-step chunk)
#define HBYTES (HSLOTS * RSLOT)    // 23040
#define QSTEP 512                  // qin per step: 64 lanes * 8 B
#define QCH (HSLOTS * QSTEP)       // 5120

typedef __attribute__((address_space(3))) char lds_c;
typedef __attribute__((address_space(1))) const char g_c;

__device__ __forceinline__ float sigmf(float x) {
    float e = __builtin_amdgcn_exp2f(-1.44269504f * x);
    return __builtin_amdgcn_rcpf(1.0f + e);
}
__device__ __forceinline__ float rcpf(float x) { return __builtin_amdgcn_rcpf(x); }

// sum over each 16-lane row via full-rate DPP adds; result broadcast to all 16
__device__ __forceinline__ float row_sum16(float x) {
    x += __int_as_float(__builtin_amdgcn_update_dpp(0, __float_as_int(x), 0xB1, 0xF, 0xF, true));
    x += __int_as_float(__builtin_amdgcn_update_dpp(0, __float_as_int(x), 0x4E, 0xF, 0xF, true));
    x += __int_as_float(__builtin_amdgcn_update_dpp(0, __float_as_int(x), 0x141, 0xF, 0xF, true));
    x += __int_as_float(__builtin_amdgcn_update_dpp(0, __float_as_int(x), 0x140, 0xF, 0xF, true));
    return x;
}

// ---------------------------------------------------------------------------
// Kernel A (proven): pointwise parameter mapping.
// ---------------------------------------------------------------------------
__global__ __launch_bounds__(256) void shm_param_kernel(
    const float* __restrict__ xc, const float* __restrict__ lo,
    float* __restrict__ R, float* __restrict__ V)
{
    const int tid = blockIdx.x * 256 + threadIdx.x;
    const int m  = tid & 15;
    const int bt = tid >> 4;

    const float* lr = lo + (size_t)bt * 128 + m;
    const float r0 = lr[0],   r1 = lr[16],  r2 = lr[32],  r3 = lr[48];
    const float r4 = lr[64],  r5 = lr[80],  r6 = lr[96],  r7 = lr[112];

    const float* xp = xc + (size_t)bt * 3;
    const float prec = xp[0], pet = xp[1], temp = xp[2];
    const bool frozen = (temp < 0.f);
    const float tpos = frozen ? 0.f : temp;

    const float dd    = 10.f * sigmf(r0);
    const float sm    = tpos * dd;
    const float f_thr = fmaf(sigmf(r1), 50.f, 10.f);
    const float sumax = fmaf(sigmf(r2), 680.f, 20.f);
    const float beta  = fmaf(sigmf(r3), 5.f, 1.f);
    const float perc  = sigmf(r4);
    const float rkf   = rcpf(fmaf(sigmf(r5), 19.f, 1.f));
    const float rki   = rcpf(fmaf(sigmf(r6), 99.f, 1.f));
    const float rkb   = rcpf(fmaf(sigmf(r7), 990.f, 10.f));

    float4* Rp = (float4*)(R + (size_t)tid * 8);
    Rp[0] = make_float4(sm, f_thr, sumax, beta);
    Rp[1] = make_float4(perc, rkf, rki, rkb);
    if (m == 0)
        *(float4*)(V + (size_t)bt * 4) =
            make_float4(frozen ? prec : 0.f, frozen ? 0.f : prec, 0.9f * pet, 0.f);
}

// ---------------------------------------------------------------------------
// Kernel B: two-wave pipelined serial scan. 64 blocks x 128 threads (2 waves).
// wave0 = nonlinear chain (ss, su; the only irreducibly serial math):
//   region r (r<=145): read A+V of chunk r from half[h=r&1], 10 chain steps,
//   write {qf_in, qu_out} into qring[h].
// wave1 = producer + linear reservoirs (sf, si, sb), one region behind:
//   region r: (r>=1) read B + qin of chunk r-1 from half[1-h]/qring[1-h];
//   (r<=144) THEN issue 30 DMAs for chunk r+1 into half[1-h] (read-before-
//   overwrite); (r>=1) reservoirs + 16-model mean + stores.
// __syncthreads() once per region: its implicit vmcnt(0)/lgkm(0) drain IS the
// ledger -- wave1's DMAs land before the barrier, wave0's qin writes drain too.
// ---------------------------------------------------------------------------
__global__ __launch_bounds__(128, 1) void shm_serial_kernel(
    const float* __restrict__ R,
    const float* __restrict__ V,
    float* __restrict__ out)
{
    __shared__ __align__(16) char pring[2 * HBYTES];   // 46080 B params
    __shared__ __align__(16) char qring[2 * QCH];      // 10240 B qin

    const int lane = threadIdx.x & 63;
    const int wid  = threadIdx.x >> 6;
    const int m = lane & 15;
    const int b = (blockIdx.x * 64 + lane) >> 4;
    float* op = out + (size_t)b * T_LEN;

    lds_c* pl = (lds_c*)pring;

    // wave0 state
    float ss = 0.f, su = 5.f;
    // wave1 state
    float sf = 1.f, si = 10.f, sb = 15.f, qkeep = 0.f;
    const float* pRd = R + ((size_t)b * T_LEN * 16 + m) * 8;
    const float* pVd = V + (size_t)b * T_LEN * 4 + (lane & 3);

#define FOR10(X) X(0) X(1) X(2) X(3) X(4) X(5) X(6) X(7) X(8) X(9)

#define PISSUE(J) {                                                          \
    __builtin_amdgcn_global_load_lds((g_c*)pRd,     pl + wb + (J)*RSLOT,        16, 0, 0); \
    __builtin_amdgcn_global_load_lds((g_c*)(pRd+4), pl + wb + (J)*RSLOT + 1024, 16, 0, 0); \
    __builtin_amdgcn_global_load_lds((g_c*)pVd,     pl + wb + (J)*RSLOT + 2048, 4, 0, 0);  \
    pRd += 128; pVd += 4; }

#define NLOAD(J)                                                             \
    float4 A##J = *(const float4*)(pring + ph + (J)*RSLOT + lane*16);        \
    float4 W##J = *(const float4*)(pring + ph + (J)*RSLOT + 2048 + ((lane & ~3)<<2));

#define NSTEP(J) {                                                           \
    const float smv = A##J.x, f_thr = A##J.y, sumax = A##J.z, beta = A##J.w; \
    const float sn = W##J.x, lpq = W##J.y, et09 = W##J.z;                    \
    const float inv = rcpf(sumax);                                           \
    const float e_i = et09 * inv;                                            \
    const float qs_out = fminf(ss, smv);                                     \
    ss = (ss - qs_out) + sn;                                                 \
    const float qsp = qs_out + lpq;                                          \
    const float qf_in = fmaxf(0.f, qsp - f_thr);                             \
    const float qu_in = fminf(qsp, f_thr);                                   \
    const float u = su * inv;                                                \
    const float psi = __builtin_amdgcn_exp2f(beta * __builtin_amdgcn_logf(u)); \
    const float su_t = fmaf(qu_in, 1.f - psi, su);                           \
    const float su2 = fminf(su_t, sumax);                                    \
    const float ovf = fmaxf(0.f, su_t - sumax);                              \
    const float qu_out = fmaf(qu_in, psi, ovf);                              \
    const float u2 = su2 * inv;                                              \
    const float ret = (u2 <= 0.8f) ? su2 * e_i : et09;                       \
    su = fmaxf(0.f, su2 - ret);                                              \
    *(float2*)(qring + qh + (J)*QSTEP + lane*8) = make_float2(qf_in, qu_out); \
}

#define PLOAD(J)                                                             \
    float4 B##J = *(const float4*)(pring + rb + (J)*RSLOT + 1024 + lane*16); \
    float2 Q##J = *(const float2*)(qring + qrb + (J)*QSTEP + lane*8);

#define LSTEP(J, tt) {                                                       \
    const float perc = B##J.x, rkf = B##J.y, rki = B##J.z, rkb = B##J.w;     \
    const float qf_in = Q##J.x, qu_out = Q##J.y;                             \
    sf += qf_in; const float qf_out = sf * rkf; sf -= qf_out;                \
    const float qi_in = qu_out * perc;                                       \
    si += qi_in; const float qi_out = si * rki; si -= qi_out;                \
    sb += (qu_out - qi_in); const float qb_out = sb * rkb; sb -= qb_out;     \
    const float q = row_sum16(qf_out + qi_out + qb_out) * 0.0625f;           \
    qkeep = (m == ((tt) & 15)) ? q : qkeep;                                  \
    if (((tt) & 15) == 15) op[((tt) & ~15) + m] = qkeep;                     \
}

    // prologue: wave1 issues chunk 0 into half 0
    if (wid == 1) {
        uint32_t wb = 0;
        FOR10(PISSUE)
    }
    __syncthreads();

    for (int r = 0; r <= 146; ++r) {
        const int h = r & 1;
        if (wid == 0) {
            if (r <= 145) {
                const uint32_t ph = (uint32_t)h * HBYTES;
                const uint32_t qh = (uint32_t)h * QCH;
                FOR10(NLOAD)
                FOR10(NSTEP)
            }
        } else {
            const uint32_t rb  = (uint32_t)(1 - h) * HBYTES;
            const uint32_t qrb = (uint32_t)(1 - h) * QCH;
            if (r >= 1) {
                FOR10(PLOAD)
                if (r <= 144) { uint32_t wb = rb; FOR10(PISSUE) }
                const int t0 = 10 * (r - 1);
                LSTEP(0, t0)     LSTEP(1, t0 + 1) LSTEP(2, t0 + 2)
                LSTEP(3, t0 + 3) LSTEP(4, t0 + 4) LSTEP(5, t0 + 5)
                LSTEP(6, t0 + 6) LSTEP(7, t0 + 7) LSTEP(8, t0 + 8)
                LSTEP(9, t0 + 9)
            } else {
                uint32_t wb = HBYTES;   // r==0: issue chunk 1 into half 1
                FOR10(PISSUE)
            }
        }
        __syncthreads();
    }

    if (wid == 1 && m < 4) op[1456 + m] = qkeep;   // t = 1456..1459

#undef FOR10
#undef PISSUE
#undef NLOAD
#undef NSTEP
#undef PLOAD
#undef LSTEP
}

// ---------------------------------------------------------------------------
// Fallback (proven round-2 kernel) if ws_size is too small.
// ---------------------------------------------------------------------------
#define CS 10
#define NCHUNK 146
#define IST 66

__device__ __forceinline__ float lane0f(float x) {
    return __int_as_float(__builtin_amdgcn_readlane(__float_as_int(x), 0));
}

__global__ __launch_bounds__(256, 1) void shm_pc_kernel(
    const float* __restrict__ xc, const float* __restrict__ lo,
    float* __restrict__ out)
{
    __shared__ float pbuf[2][CS][8][IST];
    __shared__ float bbuf[2][CS][4][4];

    const int lane  = threadIdx.x & 63;
    const int wid   = threadIdx.x >> 6;
    const int bbase = blockIdx.x * 4;

    const int ip = lane >> 3;
    const float A  = (ip==1)?10.f : (ip==2)?20.f : (ip==3)?1.f :
                     (ip==5)?1.f  : (ip==6)?1.f  : (ip==7)?10.f : 0.f;
    const float Bc = (ip==0)?10.f : (ip==1)?50.f : (ip==2)?680.f : (ip==3)?5.f :
                     (ip==4)?1.f  : (ip==5)?19.f : (ip==6)?99.f  : 990.f;
    const bool drcp = (ip >= 5);
    const bool dsm  = (ip == 0);
    const int  mm   = (2*lane) & 15;

    auto produce = [&](int cc, int buf) {
        const int t0 = cc * CS;
        float2 raw[14];
        float xr0[14], xr1[14], xr2[14];
#pragma unroll
        for (int r = 0; r < 14; ++r) {
            const int tau = (wid - 1) + 3 * r;
            if (tau < 40) {
                const int g  = tau / CS;
                const int tl = tau - g * CS;
                const size_t rowoff = (size_t)(bbase + g) * T_LEN + (t0 + tl);
                raw[r] = *(const float2*)(lo + rowoff * 128 + 2 * lane);
                if (lane == 0) {
                    const float* xp = xc + rowoff * 3;
                    xr0[r] = xp[0]; xr1[r] = xp[1]; xr2[r] = xp[2];
                }
            }
        }
#pragma unroll
        for (int r = 0; r < 14; ++r) {
            const int tau = (wid - 1) + 3 * r;
            if (tau < 40) {
                const int g  = tau / CS;
                const int tl = tau - g * CS;
                const float prec = lane0f(xr0[r]);
                const float pet  = lane0f(xr1[r]);
                const float temp = lane0f(xr2[r]);
                const bool frozen = (temp < 0.f);
                const float tpos = frozen ? 0.f : temp;
                const float sn   = frozen ? prec : 0.f;
                const float lpq  = frozen ? 0.f : prec;
                const float et09 = 0.9f * pet;

                float v0 = fmaf(sigmf(raw[r].x), Bc, A);
                float v1 = fmaf(sigmf(raw[r].y), Bc, A);
                v0 = drcp ? rcpf(v0) : v0;
                v1 = drcp ? rcpf(v1) : v1;
                v0 = dsm ? v0 * tpos : v0;
                v1 = dsm ? v1 * tpos : v1;

                float* dst = &pbuf[buf][tl][ip][g * 16 + mm];
                *(float2*)dst = make_float2(v0, v1);
                if (lane == 0)
                    *(float4*)&bbuf[buf][tl][g][0] = make_float4(sn, lpq, et09, 0.f);
            }
        }
    };

    const int g = lane >> 4, m = lane & 15;
    float ss = 0.f, sf = 1.f, su = 5.f, si = 10.f, sb = 15.f;
    float* op = out + (size_t)(bbase + g) * T_LEN;

    if (wid != 0) produce(0, 0);
    __syncthreads();

    for (int c = 0; c < NCHUNK; ++c) {
        if (wid == 0) {
            const int buf = c & 1;
#pragma unroll
            for (int tl = 0; tl < CS; ++tl) {
                const float* rec = &pbuf[buf][tl][0][lane];
                const float sm    = rec[0 * IST];
                const float f_thr = rec[1 * IST];
                const float sumax = rec[2 * IST];
                const float beta  = rec[3 * IST];
                const float perc  = rec[4 * IST];
                const float rkf   = rec[5 * IST];
                const float rki   = rec[6 * IST];
                const float rkb   = rec[7 * IST];
                const float4 bx = *(const float4*)&bbuf[buf][tl][g][0];

                float qs_out = fminf(ss, sm);
                ss = ss - qs_out + bx.x;
                float qsp = qs_out + bx.y;
                float qf_in = fmaxf(0.f, qsp - f_thr);
                float qu_in = fminf(qsp, f_thr);
                sf += qf_in;
                float qf_out = sf * rkf;
                sf -= qf_out;
                float inv_sumax = rcpf(sumax);
                float u = su * inv_sumax;
                float psi = __builtin_amdgcn_exp2f(beta * __builtin_amdgcn_logf(u));
                float su_temp = fmaf(qu_in, 1.f - psi, su);
                su = fminf(su_temp, sumax);
                float ovf = fmaxf(0.f, su_temp - sumax);
                float qu_out = fmaf(qu_in, psi, ovf);
                float pwp = 0.8f * sumax;
                float ktheta = (su <= pwp) ? su * inv_sumax : 1.f;
                float ret = bx.z * ktheta;
                su = fmaxf(0.f, su - ret);
                float qi_in = qu_out * perc;
                si += qi_in;
                float qi_out = si * rki;
                si -= qi_out;
                float qb_in = qu_out - qi_in;
                sb += qb_in;
                float qb_out = sb * rkb;
                sb -= qb_out;

                float q = row_sum16(qf_out + qi_out + qb_out) * 0.0625f;
                if (m == 0) op[c * CS + tl] = q;
            }
        } else if (c + 1 < NCHUNK) {
            produce(c + 1, (c + 1) & 1);
        }
        __syncthreads();
    }
}

extern "C" void kernel_launch(void* const* d_in, const int* in_sizes, int n_in,
                              void* d_out, int out_size, void* d_ws, size_t ws_size,
                              hipStream_t stream) {
    const float* xc = (const float*)d_in[0];   // [256,1460,3]
    const float* lo = (const float*)d_in[1];   // [256,1460,128]
    float* out = (float*)d_out;                // [256,1460,1]

    const size_t R_BYTES = (size_t)NREC * 32;  // 191,365,120
    const size_t V_BYTES = (size_t)NBT * 16;   //   5,980,160

    if (ws_size >= R_BYTES + V_BYTES) {
        float* R = (float*)d_ws;
        float* V = (float*)((char*)d_ws + R_BYTES);
        shm_param_kernel<<<dim3(NREC / 256), dim3(256), 0, stream>>>(xc, lo, R, V);
        shm_serial_kernel<<<dim3(64), dim3(128), 0, stream>>>(R, V, out);
    } else {
        shm_pc_kernel<<<dim3(64), dim3(256), 0, stream>>>(xc, lo, out);
    }
}

// Round 16
// 191.019 us; speedup vs baseline: 3.2501x; 1.1010x over previous
//
#include <hip/hip_runtime.h>
#include <stdint.h>

#define T_LEN 1460
#define NBT (256 * T_LEN)          // 373,760 (b,t) records
#define NREC (NBT * 16)            // 5,980,160 chain records
#define RSLOT 2304                 // slot: 1024 (A) + 1024 (B) + 256 (V)
#define HSLOTS 20                  // slots per half (20-step chunk; 1460=73*20)
#define HBYTES (HSLOTS * RSLOT)    // 46080
#define QSTEP 512                  // qin per step: 64 lanes * 8 B
#define QCH (HSLOTS * QSTEP)       // 10240

typedef __attribute__((address_space(3))) char lds_c;
typedef __attribute__((address_space(1))) const char g_c;

__device__ __forceinline__ float sigmf(float x) {
    float e = __builtin_amdgcn_exp2f(-1.44269504f * x);
    return __builtin_amdgcn_rcpf(1.0f + e);
}
__device__ __forceinline__ float rcpf(float x) { return __builtin_amdgcn_rcpf(x); }

// sum over each 16-lane row via full-rate DPP adds; result broadcast to all 16
__device__ __forceinline__ float row_sum16(float x) {
    x += __int_as_float(__builtin_amdgcn_update_dpp(0, __float_as_int(x), 0xB1, 0xF, 0xF, true));
    x += __int_as_float(__builtin_amdgcn_update_dpp(0, __float_as_int(x), 0x4E, 0xF, 0xF, true));
    x += __int_as_float(__builtin_amdgcn_update_dpp(0, __float_as_int(x), 0x141, 0xF, 0xF, true));
    x += __int_as_float(__builtin_amdgcn_update_dpp(0, __float_as_int(x), 0x140, 0xF, 0xF, true));
    return x;
}

// ---------------------------------------------------------------------------
// Kernel A (proven): pointwise parameter mapping.
// ---------------------------------------------------------------------------
__global__ __launch_bounds__(256) void shm_param_kernel(
    const float* __restrict__ xc, const float* __restrict__ lo,
    float* __restrict__ R, float* __restrict__ V)
{
    const int tid = blockIdx.x * 256 + threadIdx.x;
    const int m  = tid & 15;
    const int bt = tid >> 4;

    const float* lr = lo + (size_t)bt * 128 + m;
    const float r0 = lr[0],   r1 = lr[16],  r2 = lr[32],  r3 = lr[48];
    const float r4 = lr[64],  r5 = lr[80],  r6 = lr[96],  r7 = lr[112];

    const float* xp = xc + (size_t)bt * 3;
    const float prec = xp[0], pet = xp[1], temp = xp[2];
    const bool frozen = (temp < 0.f);
    const float tpos = frozen ? 0.f : temp;

    const float dd    = 10.f * sigmf(r0);
    const float sm    = tpos * dd;
    const float f_thr = fmaf(sigmf(r1), 50.f, 10.f);
    const float sumax = fmaf(sigmf(r2), 680.f, 20.f);
    const float beta  = fmaf(sigmf(r3), 5.f, 1.f);
    const float perc  = sigmf(r4);
    const float rkf   = rcpf(fmaf(sigmf(r5), 19.f, 1.f));
    const float rki   = rcpf(fmaf(sigmf(r6), 99.f, 1.f));
    const float rkb   = rcpf(fmaf(sigmf(r7), 990.f, 10.f));

    float4* Rp = (float4*)(R + (size_t)tid * 8);
    Rp[0] = make_float4(sm, f_thr, sumax, beta);
    Rp[1] = make_float4(perc, rkf, rki, rkb);
    if (m == 0)
        *(float4*)(V + (size_t)bt * 4) =
            make_float4(frozen ? prec : 0.f, frozen ? 0.f : prec, 0.9f * pet, 0.f);
}

// ---------------------------------------------------------------------------
// Kernel B: two-wave pipelined serial scan, 20-step regions.
// wave0 = nonlinear chain (ss, su): region r (r<=72): read A+V of chunk r
//   from half[h=r&1], 20 chain steps, write {qf_in, qu_out} into qring[h].
// wave1 = producer + linear reservoirs, one region behind: region r: (r>=1)
//   read B + qin of chunk r-1 from half[1-h]/qring[1-h]; (r<=71) then issue
//   60 DMAs for chunk r+1 into half[1-h] (read-before-overwrite in program
//   order; DMA write-back lands >=300cy after the earlier ds_reads sampled);
//   reservoirs + 16-model mean + stores.
// __syncthreads() once per region: its implicit vmcnt(0)/lgkm(0) drain IS
// the DMA/qin ledger (proven r15 scheme; no counted-vmcnt arithmetic).
// ---------------------------------------------------------------------------
__global__ __launch_bounds__(128, 1) void shm_serial_kernel(
    const float* __restrict__ R,
    const float* __restrict__ V,
    float* __restrict__ out)
{
    __shared__ __align__(16) char pring[2 * HBYTES];   // 92160 B params
    __shared__ __align__(16) char qring[2 * QCH];      // 20480 B qin

    const int lane = threadIdx.x & 63;
    const int wid  = threadIdx.x >> 6;
    const int m = lane & 15;
    const int b = (blockIdx.x * 64 + lane) >> 4;
    float* op = out + (size_t)b * T_LEN;

    lds_c* pl = (lds_c*)pring;

    // wave0 state
    float ss = 0.f, su = 5.f;
    // wave1 state
    float sf = 1.f, si = 10.f, sb = 15.f, qkeep = 0.f;
    const float* pRd = R + ((size_t)b * T_LEN * 16 + m) * 8;
    const float* pVd = V + (size_t)b * T_LEN * 4 + (lane & 3);

#define FOR20(X) X(0) X(1) X(2) X(3) X(4) X(5) X(6) X(7) X(8) X(9) \
                 X(10) X(11) X(12) X(13) X(14) X(15) X(16) X(17) X(18) X(19)

#define PISSUE(J) {                                                          \
    __builtin_amdgcn_global_load_lds((g_c*)pRd,     pl + wb + (J)*RSLOT,        16, 0, 0); \
    __builtin_amdgcn_global_load_lds((g_c*)(pRd+4), pl + wb + (J)*RSLOT + 1024, 16, 0, 0); \
    __builtin_amdgcn_global_load_lds((g_c*)pVd,     pl + wb + (J)*RSLOT + 2048, 4, 0, 0);  \
    pRd += 128; pVd += 4; }

#define NLOAD(J)                                                             \
    float4 A##J = *(const float4*)(pring + ph + (J)*RSLOT + lane*16);        \
    float4 W##J = *(const float4*)(pring + ph + (J)*RSLOT + 2048 + ((lane & ~3)<<2));

#define NSTEP(J) {                                                           \
    const float smv = A##J.x, f_thr = A##J.y, sumax = A##J.z, beta = A##J.w; \
    const float sn = W##J.x, lpq = W##J.y, et09 = W##J.z;                    \
    const float inv = rcpf(sumax);                                           \
    const float pwp = 0.8f * sumax;                                          \
    const float e_i = et09 * inv;                                            \
    const float qs_out = fminf(ss, smv);                                     \
    ss = (ss - qs_out) + sn;                                                 \
    const float qsp = qs_out + lpq;                                          \
    const float qf_in = fmaxf(0.f, qsp - f_thr);                             \
    const float qu_in = fminf(qsp, f_thr);                                   \
    const float u = su * inv;                                                \
    const float psi = __builtin_amdgcn_exp2f(beta * __builtin_amdgcn_logf(u)); \
    const float su_t = fmaf(qu_in, 1.f - psi, su);                           \
    const float su2 = fminf(su_t, sumax);                                    \
    const float ovf = fmaxf(0.f, su_t - sumax);                              \
    const float qu_out = fmaf(qu_in, psi, ovf);                              \
    const float ret = (su2 <= pwp) ? su2 * e_i : et09;                       \
    su = fmaxf(0.f, su2 - ret);                                              \
    *(float2*)(qring + qh + (J)*QSTEP + lane*8) = make_float2(qf_in, qu_out); \
}

#define PLOAD(J)                                                             \
    float4 B##J = *(const float4*)(pring + rb + (J)*RSLOT + 1024 + lane*16); \
    float2 Q##J = *(const float2*)(qring + qrb + (J)*QSTEP + lane*8);

#define LSTEP(J, tt) {                                                       \
    const float perc = B##J.x, rkf = B##J.y, rki = B##J.z, rkb = B##J.w;     \
    const float qf_in = Q##J.x, qu_out = Q##J.y;                             \
    sf += qf_in; const float qf_out = sf * rkf; sf -= qf_out;                \
    const float qi_in = qu_out * perc;                                       \
    si += qi_in; const float qi_out = si * rki; si -= qi_out;                \
    sb += (qu_out - qi_in); const float qb_out = sb * rkb; sb -= qb_out;     \
    const float q = row_sum16(qf_out + qi_out + qb_out) * 0.0625f;           \
    qkeep = (m == ((tt) & 15)) ? q : qkeep;                                  \
    if (((tt) & 15) == 15) op[((tt) & ~15) + m] = qkeep;                     \
}

    // prologue: wave1 issues chunk 0 into half 0
    if (wid == 1) {
        uint32_t wb = 0;
        FOR20(PISSUE)
    }
    __syncthreads();

    for (int r = 0; r <= 73; ++r) {
        const int h = r & 1;
        if (wid == 0) {
            if (r <= 72) {
                const uint32_t ph = (uint32_t)h * HBYTES;
                const uint32_t qh = (uint32_t)h * QCH;
                FOR20(NLOAD)
                FOR20(NSTEP)
            }
        } else {
            const uint32_t rb  = (uint32_t)(1 - h) * HBYTES;
            const uint32_t qrb = (uint32_t)(1 - h) * QCH;
            if (r >= 1) {
                FOR20(PLOAD)
                if (r <= 71) { uint32_t wb = rb; FOR20(PISSUE) }
                const int t0 = 20 * (r - 1);
                LSTEP(0,  t0)      LSTEP(1,  t0 + 1)  LSTEP(2,  t0 + 2)
                LSTEP(3,  t0 + 3)  LSTEP(4,  t0 + 4)  LSTEP(5,  t0 + 5)
                LSTEP(6,  t0 + 6)  LSTEP(7,  t0 + 7)  LSTEP(8,  t0 + 8)
                LSTEP(9,  t0 + 9)  LSTEP(10, t0 + 10) LSTEP(11, t0 + 11)
                LSTEP(12, t0 + 12) LSTEP(13, t0 + 13) LSTEP(14, t0 + 14)
                LSTEP(15, t0 + 15) LSTEP(16, t0 + 16) LSTEP(17, t0 + 17)
                LSTEP(18, t0 + 18) LSTEP(19, t0 + 19)
            } else {
                uint32_t wb = HBYTES;   // r==0: issue chunk 1 into half 1
                FOR20(PISSUE)
            }
        }
        __syncthreads();
    }

    if (wid == 1 && m < 4) op[1456 + m] = qkeep;   // t = 1456..1459

#undef FOR20
#undef PISSUE
#undef NLOAD
#undef NSTEP
#undef PLOAD
#undef LSTEP
}

// ---------------------------------------------------------------------------
// Fallback (proven round-2 kernel) if ws_size is too small.
// ---------------------------------------------------------------------------
#define CS 10
#define NCHUNK 146
#define IST 66

__device__ __forceinline__ float lane0f(float x) {
    return __int_as_float(__builtin_amdgcn_readlane(__float_as_int(x), 0));
}

__global__ __launch_bounds__(256, 1) void shm_pc_kernel(
    const float* __restrict__ xc, const float* __restrict__ lo,
    float* __restrict__ out)
{
    __shared__ float pbuf[2][CS][8][IST];
    __shared__ float bbuf[2][CS][4][4];

    const int lane  = threadIdx.x & 63;
    const int wid   = threadIdx.x >> 6;
    const int bbase = blockIdx.x * 4;

    const int ip = lane >> 3;
    const float A  = (ip==1)?10.f : (ip==2)?20.f : (ip==3)?1.f :
                     (ip==5)?1.f  : (ip==6)?1.f  : (ip==7)?10.f : 0.f;
    const float Bc = (ip==0)?10.f : (ip==1)?50.f : (ip==2)?680.f : (ip==3)?5.f :
                     (ip==4)?1.f  : (ip==5)?19.f : (ip==6)?99.f  : 990.f;
    const bool drcp = (ip >= 5);
    const bool dsm  = (ip == 0);
    const int  mm   = (2*lane) & 15;

    auto produce = [&](int cc, int buf) {
        const int t0 = cc * CS;
        float2 raw[14];
        float xr0[14], xr1[14], xr2[14];
#pragma unroll
        for (int r = 0; r < 14; ++r) {
            const int tau = (wid - 1) + 3 * r;
            if (tau < 40) {
                const int g  = tau / CS;
                const int tl = tau - g * CS;
                const size_t rowoff = (size_t)(bbase + g) * T_LEN + (t0 + tl);
                raw[r] = *(const float2*)(lo + rowoff * 128 + 2 * lane);
                if (lane == 0) {
                    const float* xp = xc + rowoff * 3;
                    xr0[r] = xp[0]; xr1[r] = xp[1]; xr2[r] = xp[2];
                }
            }
        }
#pragma unroll
        for (int r = 0; r < 14; ++r) {
            const int tau = (wid - 1) + 3 * r;
            if (tau < 40) {
                const int g  = tau / CS;
                const int tl = tau - g * CS;
                const float prec = lane0f(xr0[r]);
                const float pet  = lane0f(xr1[r]);
                const float temp = lane0f(xr2[r]);
                const bool frozen = (temp < 0.f);
                const float tpos = frozen ? 0.f : temp;
                const float sn   = frozen ? prec : 0.f;
                const float lpq  = frozen ? 0.f : prec;
                const float et09 = 0.9f * pet;

                float v0 = fmaf(sigmf(raw[r].x), Bc, A);
                float v1 = fmaf(sigmf(raw[r].y), Bc, A);
                v0 = drcp ? rcpf(v0) : v0;
                v1 = drcp ? rcpf(v1) : v1;
                v0 = dsm ? v0 * tpos : v0;
                v1 = dsm ? v1 * tpos : v1;

                float* dst = &pbuf[buf][tl][ip][g * 16 + mm];
                *(float2*)dst = make_float2(v0, v1);
                if (lane == 0)
                    *(float4*)&bbuf[buf][tl][g][0] = make_float4(sn, lpq, et09, 0.f);
            }
        }
    };

    const int g = lane >> 4, m = lane & 15;
    float ss = 0.f, sf = 1.f, su = 5.f, si = 10.f, sb = 15.f;
    float* op = out + (size_t)(bbase + g) * T_LEN;

    if (wid != 0) produce(0, 0);
    __syncthreads();

    for (int c = 0; c < NCHUNK; ++c) {
        if (wid == 0) {
            const int buf = c & 1;
#pragma unroll
            for (int tl = 0; tl < CS; ++tl) {
                const float* rec = &pbuf[buf][tl][0][lane];
                const float sm    = rec[0 * IST];
                const float f_thr = rec[1 * IST];
                const float sumax = rec[2 * IST];
                const float beta  = rec[3 * IST];
                const float perc  = rec[4 * IST];
                const float rkf   = rec[5 * IST];
                const float rki   = rec[6 * IST];
                const float rkb   = rec[7 * IST];
                const float4 bx = *(const float4*)&bbuf[buf][tl][g][0];

                float qs_out = fminf(ss, sm);
                ss = ss - qs_out + bx.x;
                float qsp = qs_out + bx.y;
                float qf_in = fmaxf(0.f, qsp - f_thr);
                float qu_in = fminf(qsp, f_thr);
                sf += qf_in;
                float qf_out = sf * rkf;
                sf -= qf_out;
                float inv_sumax = rcpf(sumax);
                float u = su * inv_sumax;
                float psi = __builtin_amdgcn_exp2f(beta * __builtin_amdgcn_logf(u));
                float su_temp = fmaf(qu_in, 1.f - psi, su);
                su = fminf(su_temp, sumax);
                float ovf = fmaxf(0.f, su_temp - sumax);
                float qu_out = fmaf(qu_in, psi, ovf);
                float pwp = 0.8f * sumax;
                float ktheta = (su <= pwp) ? su * inv_sumax : 1.f;
                float ret = bx.z * ktheta;
                su = fmaxf(0.f, su - ret);
                float qi_in = qu_out * perc;
                si += qi_in;
                float qi_out = si * rki;
                si -= qi_out;
                float qb_in = qu_out - qi_in;
                sb += qb_in;
                float qb_out = sb * rkb;
                sb -= qb_out;

                float q = row_sum16(qf_out + qi_out + qb_out) * 0.0625f;
                if (m == 0) op[c * CS + tl] = q;
            }
        } else if (c + 1 < NCHUNK) {
            produce(c + 1, (c + 1) & 1);
        }
        __syncthreads();
    }
}

extern "C" void kernel_launch(void* const* d_in, const int* in_sizes, int n_in,
                              void* d_out, int out_size, void* d_ws, size_t ws_size,
                              hipStream_t stream) {
    const float* xc = (const float*)d_in[0];   // [256,1460,3]
    const float* lo = (const float*)d_in[1];   // [256,1460,128]
    float* out = (float*)d_out;                // [256,1460,1]

    const size_t R_BYTES = (size_t)NREC * 32;  // 191,365,120
    const size_t V_BYTES = (size_t)NBT * 16;   //   5,980,160

    if (ws_size >= R_BYTES + V_BYTES) {
        float* R = (float*)d_ws;
        float* V = (float*)((char*)d_ws + R_BYTES);
        shm_param_kernel<<<dim3(NREC / 256), dim3(256), 0, stream>>>(xc, lo, R, V);
        shm_serial_kernel<<<dim3(64), dim3(128), 0, stream>>>(R, V, out);
    } else {
        shm_pc_kernel<<<dim3(64), dim3(256), 0, stream>>>(xc, lo, out);
    }
}